// Round 2
// baseline (1833.803 us; speedup 1.0000x reference)
//
#include <hip/hip_runtime.h>

#define VOCAB 32000
#define NTOK  1024
#define HS    2048
#define HT    4096

typedef __attribute__((ext_vector_type(8))) short bf16x8;
typedef __attribute__((ext_vector_type(4))) float f32x4;

__device__ __forceinline__ unsigned short f2bf(float f){
  unsigned u = __float_as_uint(f);
  u += 0x7fffu + ((u >> 16) & 1u);   // round-to-nearest-even
  return (unsigned short)(u >> 16);
}
__device__ __forceinline__ unsigned pack2(float a, float b){
  return (unsigned)f2bf(a) | ((unsigned)f2bf(b) << 16);
}
__device__ __forceinline__ float blo(unsigned u){ return __uint_as_float(u << 16); }
__device__ __forceinline__ float bhi(unsigned u){ return __uint_as_float(u & 0xffff0000u); }

// ---------------- fp32 -> bf16 (activations) ----------------
__global__ __launch_bounds__(256) void cvt_f32_bf16(const float* __restrict__ in,
                                                    unsigned short* __restrict__ out, int n4){
  int i = blockIdx.x * 256 + threadIdx.x;
  if (i < n4){
    float4 v = ((const float4*)in)[i];
    uint2 o;
    o.x = pack2(v.x, v.y);
    o.y = pack2(v.z, v.w);
    ((uint2*)out)[i] = o;
  }
}

// ---------------- GEMM: C[m,v] = sum_k A[m,k]*W[v,k] + bias[v] ----------------
// A: [NTOK,K] bf16 (pre-converted). W: [VOCAB,K] fp32, converted bf16 in-flight.
// Tile 128x128x32, 256 threads = 4 waves, each wave 64x64 (4x4 MFMA 16x16x32).
//
// LDS layout is FRAGMENT-MAJOR: tile = 8 groups of (16 rows x 32 k); each group
// is 64 chunks of 16B stored in exact MFMA-lane order (lane l = kq*16 + ar holds
// row ar, k kq*8..kq*8+7). Both staging writes and ds_read_b128 fragment reads
// are base + lane*16 sequential -> zero bank conflicts (vs 8-way with LDT=40).
__global__ __launch_bounds__(256) void gemm_logits(
    const unsigned short* __restrict__ A,
    const float* __restrict__ W,
    const float* __restrict__ bias,
    unsigned short* __restrict__ C,   // [NTOK, VOCAB] bf16
    int K)
{
  __shared__ unsigned short As[8 * 512];   // 8 KB
  __shared__ unsigned short Bs[8 * 512];   // 8 KB

  const int tid  = threadIdx.x;
  const int lane = tid & 63;
  const int wave = tid >> 6;
  // grid: blockIdx.x = m-tile (8), blockIdx.y = vocab-tile (250).
  // Co-resident blocks then share v-slices of W across all m-tiles -> W read
  // from HBM ~once, re-reads hit L2/L3.
  const int m0 = blockIdx.x * 128;
  const int v0 = blockIdx.y * 128;
  const int wm = (wave >> 1) * 64;
  const int wn = (wave & 1) * 64;

  const int ar = lane & 15;   // row-in-group == MFMA m/n index
  const int kq = lane >> 4;   // k-quad (8 bf16 each)

  const f32x4 zero = {0.f, 0.f, 0.f, 0.f};
  f32x4 acc[4][4];
#pragma unroll
  for (int i = 0; i < 4; i++)
#pragma unroll
    for (int j = 0; j < 4; j++) acc[i][j] = zero;

  const int NT = K >> 5;

  // staging: each wave covers groups {wave, wave+4}
  const unsigned short* apg0 = A + (size_t)(m0 + wave * 16 + ar) * K + kq * 8;
  const unsigned short* apg1 = apg0 + (size_t)64 * K;
  const float* wpg0 = W + (size_t)(v0 + wave * 16 + ar) * K + kq * 8;
  const float* wpg1 = wpg0 + (size_t)64 * K;

  uint4 a0, a1;
  float4 w00, w01, w10, w11;
  a0  = *(const uint4*)(apg0);
  a1  = *(const uint4*)(apg1);
  w00 = *(const float4*)(wpg0);
  w01 = *(const float4*)(wpg0 + 4);
  w10 = *(const float4*)(wpg1);
  w11 = *(const float4*)(wpg1 + 4);

  for (int kt = 0; kt < NT; ++kt){
    __syncthreads();
    // regs -> LDS (lane-sequential, conflict-free)
    *(uint4*)(As + wave * 512 + lane * 8)       = a0;
    *(uint4*)(As + (wave + 4) * 512 + lane * 8) = a1;
    *(uint4*)(Bs + wave * 512 + lane * 8) =
        make_uint4(pack2(w00.x, w00.y), pack2(w00.z, w00.w),
                   pack2(w01.x, w01.y), pack2(w01.z, w01.w));
    *(uint4*)(Bs + (wave + 4) * 512 + lane * 8) =
        make_uint4(pack2(w10.x, w10.y), pack2(w10.z, w10.w),
                   pack2(w11.x, w11.y), pack2(w11.z, w11.w));
    __syncthreads();
    // prefetch next tile into regs (overlaps the MFMAs below)
    if (kt + 1 < NT){
      const int k0 = (kt + 1) << 5;
      a0  = *(const uint4*)(apg0 + k0);
      a1  = *(const uint4*)(apg1 + k0);
      w00 = *(const float4*)(wpg0 + k0);
      w01 = *(const float4*)(wpg0 + k0 + 4);
      w10 = *(const float4*)(wpg1 + k0);
      w11 = *(const float4*)(wpg1 + k0 + 4);
    }
    // LDS -> frags -> MFMA (reads are base + lane*16 sequential)
    bf16x8 af[4], bf[4];
#pragma unroll
    for (int i = 0; i < 4; i++){
      af[i] = *(const bf16x8*)(As + ((wm >> 4) + i) * 512 + lane * 8);
      bf[i] = *(const bf16x8*)(Bs + ((wn >> 4) + i) * 512 + lane * 8);
    }
#pragma unroll
    for (int i = 0; i < 4; i++)
#pragma unroll
      for (int j = 0; j < 4; j++)
        acc[i][j] = __builtin_amdgcn_mfma_f32_16x16x32_bf16(af[i], bf[j], acc[i][j], 0, 0, 0);
  }

  // epilogue: C/D layout col = lane&15, row = (lane>>4)*4 + reg  [m89-verified]
  const int rq = lane >> 4;
#pragma unroll
  for (int j = 0; j < 4; j++){
    const int v = v0 + wn + j * 16 + ar;
    const float bv = bias[v];
#pragma unroll
    for (int i = 0; i < 4; i++){
      const int mbase = m0 + wm + i * 16 + rq * 4;
#pragma unroll
      for (int r = 0; r < 4; r++){
        C[(size_t)(mbase + r) * VOCAB + v] = f2bf(acc[i][j][r] + bv);
      }
    }
  }
}

// ---------------- per-row logsumexp over VOCAB ----------------
__global__ __launch_bounds__(256) void row_stats(const unsigned short* __restrict__ L,
                                                 float* __restrict__ lse){
  const int row = blockIdx.x;
  const uint4* p = (const uint4*)(L + (size_t)row * VOCAB);
  float mx = -3.0e38f;
  for (int i = threadIdx.x; i < VOCAB / 8; i += 256){
    uint4 u = p[i];
    float f0 = blo(u.x), f1 = bhi(u.x), f2 = blo(u.y), f3 = bhi(u.y);
    float f4 = blo(u.z), f5 = bhi(u.z), f6 = blo(u.w), f7 = bhi(u.w);
    mx = fmaxf(mx, fmaxf(fmaxf(fmaxf(f0, f1), fmaxf(f2, f3)),
                         fmaxf(fmaxf(f4, f5), fmaxf(f6, f7))));
  }
#pragma unroll
  for (int off = 1; off < 64; off <<= 1) mx = fmaxf(mx, __shfl_xor(mx, off));
  __shared__ float sm[4], ss[4];
  if ((threadIdx.x & 63) == 0) sm[threadIdx.x >> 6] = mx;
  __syncthreads();
  mx = fmaxf(fmaxf(sm[0], sm[1]), fmaxf(sm[2], sm[3]));
  float s = 0.f;
  for (int i = threadIdx.x; i < VOCAB / 8; i += 256){
    uint4 u = p[i];
    s += __expf(blo(u.x) - mx) + __expf(bhi(u.x) - mx)
       + __expf(blo(u.y) - mx) + __expf(bhi(u.y) - mx)
       + __expf(blo(u.z) - mx) + __expf(bhi(u.z) - mx)
       + __expf(blo(u.w) - mx) + __expf(bhi(u.w) - mx);
  }
#pragma unroll
  for (int off = 1; off < 64; off <<= 1) s += __shfl_xor(s, off);
  if ((threadIdx.x & 63) == 0) ss[threadIdx.x >> 6] = s;
  __syncthreads();
  if (threadIdx.x == 0) lse[row] = mx + __logf(ss[0] + ss[1] + ss[2] + ss[3]);
}

// ---------------- JSD + CE, accumulate scalar ----------------
__device__ __forceinline__ float jsd_term(float sl, float tl, float ls, float lt){
  float slp = sl - ls, tlp = tl - lt;
  float sp = __expf(slp), tp = __expf(tlp);
  float lm = __logf(0.5f * (sp + tp));
  return 0.5f * (tp * (tlp - lm) + sp * (slp - lm));  // BETA = 0.5
}

__global__ __launch_bounds__(256) void jsd_ce(
    const unsigned short* __restrict__ Ls, const unsigned short* __restrict__ Lt,
    const float* __restrict__ lse_s, const float* __restrict__ lse_t,
    const int* __restrict__ labels, float* __restrict__ out)
{
  const int row = blockIdx.x;
  const float ls = lse_s[row], lt = lse_t[row];
  const uint4* ps = (const uint4*)(Ls + (size_t)row * VOCAB);
  const uint4* pt = (const uint4*)(Lt + (size_t)row * VOCAB);
  float acc = 0.f;
  for (int i = threadIdx.x; i < VOCAB / 8; i += 256){
    uint4 us = ps[i], ut = pt[i];
    acc += jsd_term(blo(us.x), blo(ut.x), ls, lt) + jsd_term(bhi(us.x), bhi(ut.x), ls, lt);
    acc += jsd_term(blo(us.y), blo(ut.y), ls, lt) + jsd_term(bhi(us.y), bhi(ut.y), ls, lt);
    acc += jsd_term(blo(us.z), blo(ut.z), ls, lt) + jsd_term(bhi(us.z), bhi(ut.z), ls, lt);
    acc += jsd_term(blo(us.w), blo(ut.w), ls, lt) + jsd_term(bhi(us.w), bhi(ut.w), ls, lt);
  }
#pragma unroll
  for (int off = 1; off < 64; off <<= 1) acc += __shfl_xor(acc, off);
  __shared__ float sa[4];
  if ((threadIdx.x & 63) == 0) sa[threadIdx.x >> 6] = acc;
  __syncthreads();
  if (threadIdx.x == 0){
    float tot = sa[0] + sa[1] + sa[2] + sa[3];
    float res = tot * (0.5f / (float)NTOK);          // WEIGHT_SOFT * jsd / N
    int lab = labels[row];
    if (lab != -100){
      float sl_lab = __uint_as_float((unsigned)Ls[(size_t)row * VOCAB + lab] << 16);
      res += (ls - sl_lab) * (0.5f / (float)NTOK);   // WEIGHT_HARD * nll / N
    }
    atomicAdd(out, res);
  }
}

extern "C" void kernel_launch(void* const* d_in, const int* in_sizes, int n_in,
                              void* d_out, int out_size, void* d_ws, size_t ws_size,
                              hipStream_t stream){
  (void)in_sizes; (void)n_in; (void)out_size; (void)ws_size;
  const float* s_in = (const float*)d_in[0];
  const float* s_w  = (const float*)d_in[1];
  const float* t_in = (const float*)d_in[2];
  const float* t_w  = (const float*)d_in[3];
  const int*   lab  = (const int*)d_in[4];
  const float* s_b  = (const float*)d_in[5];
  const float* t_b  = (const float*)d_in[6];
  float* out = (float*)d_out;

  char* ws = (char*)d_ws;
  size_t off = 0;
  auto alloc = [&](size_t b){ void* p = ws + off; off += (b + 255) & ~(size_t)255; return p; };
  unsigned short* As_bf = (unsigned short*)alloc((size_t)NTOK * HS * 2);
  unsigned short* At_bf = (unsigned short*)alloc((size_t)NTOK * HT * 2);
  unsigned short* Ls    = (unsigned short*)alloc((size_t)NTOK * VOCAB * 2);
  unsigned short* Lt    = (unsigned short*)alloc((size_t)NTOK * VOCAB * 2);
  float* lse_s = (float*)alloc(NTOK * 4);
  float* lse_t = (float*)alloc(NTOK * 4);

  hipMemsetAsync(d_out, 0, sizeof(float), stream);
  cvt_f32_bf16<<<NTOK * HS / 4 / 256, 256, 0, stream>>>(s_in, As_bf, NTOK * HS / 4);
  cvt_f32_bf16<<<NTOK * HT / 4 / 256, 256, 0, stream>>>(t_in, At_bf, NTOK * HT / 4);
  dim3 g(NTOK / 128, VOCAB / 128);   // x = m-tile (fast), y = vocab-tile
  gemm_logits<<<g, 256, 0, stream>>>(As_bf, s_w, s_b, Ls, HS);
  gemm_logits<<<g, 256, 0, stream>>>(At_bf, t_w, t_b, Lt, HT);
  row_stats<<<NTOK, 256, 0, stream>>>(Ls, lse_s);
  row_stats<<<NTOK, 256, 0, stream>>>(Lt, lse_t);
  jsd_ce<<<NTOK, 256, 0, stream>>>(Ls, Lt, lse_s, lse_t, lab, out);
}